// Round 3
// baseline (290.867 us; speedup 1.0000x reference)
//
#include <hip/hip_runtime.h>

#define TOPK 8
#define MM 32
#define MG 4    // candidates per prefetch batch
#define REPS 8  // diagnostic repetitions (writes go to d_ws)

// ---------- shared per-pixel NMS body ----------
__device__ __forceinline__ void nms_pixel(
    const float* __restrict__ coords, const float* __restrict__ P,
    int n, int hw, int HW, int* sel_out)
{
    const float THR2 = 4.0f;
    const float EPSV = 1e-6f;
    const float BIGV = 1e9f;

    const float* Pp = P + n * 12;
    float p00 = Pp[0], p01 = Pp[1], p02 = Pp[2],  p03 = Pp[3];
    float p10 = Pp[4], p11 = Pp[5], p12 = Pp[6],  p13 = Pp[7];
    float p20 = Pp[8], p21 = Pp[9], p22 = Pp[10], p23 = Pp[11];

    const float* base = coords + (size_t)n * (MM * 3) * HW + hw;
    const size_t mstride = (size_t)3 * HW;

    float kx[TOPK], ky[TOPK];
    int sel[TOPK];
#pragma unroll
    for (int s = 0; s < TOPK; ++s) { kx[s] = BIGV; ky[s] = BIGV; sel[s] = 0; }
    int cnt = 0;

    float X0[MG], X1[MG], X2[MG];
#pragma unroll
    for (int g = 0; g < MG; ++g) {
        const float* cm = base + (size_t)g * mstride;
        X0[g] = cm[0]; X1[g] = cm[HW]; X2[g] = cm[2 * HW];
    }

    for (int mb = 0; mb < MM; mb += MG) {
        if (__all(cnt >= TOPK)) break;

        float nX0[MG], nX1[MG], nX2[MG];
        if (mb + MG < MM) {
#pragma unroll
            for (int g = 0; g < MG; ++g) {
                const float* cm = base + (size_t)(mb + MG + g) * mstride;
                nX0[g] = cm[0]; nX1[g] = cm[HW]; nX2[g] = cm[2 * HW];
            }
        } else {
#pragma unroll
            for (int g = 0; g < MG; ++g) { nX0[g] = 0.f; nX1[g] = 0.f; nX2[g] = 0.f; }
        }

#pragma unroll
        for (int g = 0; g < MG; ++g) {
            int m = mb + g;
            float xc = p00 * X0[g] + p01 * X1[g] + p02 * X2[g] + p03;
            float yc = p10 * X0[g] + p11 * X1[g] + p12 * X2[g] + p13;
            float zc = p20 * X0[g] + p21 * X1[g] + p22 * X2[g] + p23;
            float z  = fmaxf(zc, EPSV);
            float x  = xc / z;
            float y  = yc / z;

            bool sup = false;
#pragma unroll
            for (int s = 0; s < TOPK; ++s) {
                float dx = kx[s] - x;
                float dy = ky[s] - y;
                sup = sup || (dx * dx + dy * dy <= THR2);
            }
            bool keep = (!sup) && (cnt < TOPK);
            if (keep) {
#pragma unroll
                for (int s = 0; s < TOPK; ++s) {
                    if (s == cnt) { kx[s] = x; ky[s] = y; sel[s] = m; }
                }
                cnt++;
            }
        }

#pragma unroll
        for (int g = 0; g < MG; ++g) { X0[g] = nX0[g]; X1[g] = nX1[g]; X2[g] = nX2[g]; }
    }

#pragma unroll
    for (int s = 0; s < TOPK; ++s) sel_out[s] = sel[s];
}

// ---------- real kernel (identical to round 2) ----------
__global__ __launch_bounds__(256) void nms_proj_kernel(
    const float* __restrict__ coords, const float* __restrict__ P,
    int* __restrict__ out, int N, int HW)
{
    int pix = blockIdx.x * blockDim.x + threadIdx.x;
    if (pix >= N * HW) return;
    int n = pix / HW;
    int hw = pix - n * HW;

    int sel[TOPK];
    nms_pixel(coords, P, n, hw, HW, sel);

    int4* o = reinterpret_cast<int4*>(out + (size_t)pix * TOPK);
    o[0] = make_int4(sel[0], sel[1], sel[2], sel[3]);
    o[1] = make_int4(sel[4], sel[5], sel[6], sel[7]);
}

// ---------- diagnostic kernel: same work x REPS, results to d_ws ----------
__global__ __launch_bounds__(256) void nms_diag_kernel(
    const float* __restrict__ coords, const float* __restrict__ P,
    int* __restrict__ ws, int N, int HW)
{
    int pix = blockIdx.x * blockDim.x + threadIdx.x;
    if (pix >= N * HW) return;
    int n = pix / HW;
    int hw = pix - n * HW;

    int total = N * HW;
#pragma unroll 1
    for (int rep = 0; rep < REPS; ++rep) {
        int sel[TOPK];
        nms_pixel(coords, P, n, hw, HW, sel);
        // distinct address per rep -> no dead-store elimination
        int4* o = reinterpret_cast<int4*>(ws + ((size_t)rep * total + pix) * TOPK);
        o[0] = make_int4(sel[0], sel[1], sel[2], sel[3]);
        o[1] = make_int4(sel[4], sel[5], sel[6], sel[7]);
    }
}

extern "C" void kernel_launch(void* const* d_in, const int* in_sizes, int n_in,
                              void* d_out, int out_size, void* d_ws, size_t ws_size,
                              hipStream_t stream) {
    const float* coords = (const float*)d_in[0];   // [N, M, 3, H, W] fp32
    const float* P      = (const float*)d_in[1];   // [N, 3, 4] fp32
    int* out            = (int*)d_out;             // [N, H, W, TOPK] int32

    int N  = in_sizes[1] / 12;                 // 16
    int HW = in_sizes[0] / (N * MM * 3);       // 19200
    int total = N * HW;

    int block = 256;
    int grid = (total + block - 1) / block;    // 1200 blocks

    // 1) real output (unchanged round-2 kernel)
    nms_proj_kernel<<<grid, block, 0, stream>>>(coords, P, out, N, HW);
    // 2) diagnostic: 8x identical workload into d_ws (78.6 MB < 450 MiB ws)
    nms_diag_kernel<<<grid, block, 0, stream>>>(coords, P, (int*)d_ws, N, HW);
}

// Round 4
// 157.298 us; speedup vs baseline: 1.8491x; 1.8491x over previous
//
#include <hip/hip_runtime.h>

#define TOPK 8
#define MM 32
#define MG 4   // candidates per prefetch batch

// CHW > 0: compile-time HW (all plane offsets become literals). CHW==0: runtime.
template<int CHW>
__global__ __launch_bounds__(256) void nms_kernel(
    const float* __restrict__ coords, const float* __restrict__ P,
    int* __restrict__ out, int rHW)
{
    const int HW = (CHW > 0) ? CHW : rHW;
    const int n  = blockIdx.y;                       // image index (block-uniform)
    const int hw = blockIdx.x * 256 + threadIdx.x;   // pixel within image
    if (hw >= HW) return;

    const float THR2 = 4.0f;
    const float EPSV = 1e-6f;
    const float BIGV = 1e9f;

    // n is block-uniform -> these become scalar s_loads
    const float* Pp = P + n * 12;
    float p00 = Pp[0], p01 = Pp[1], p02 = Pp[2],  p03 = Pp[3];
    float p10 = Pp[4], p11 = Pp[5], p12 = Pp[6],  p13 = Pp[7];
    float p20 = Pp[8], p21 = Pp[9], p22 = Pp[10], p23 = Pp[11];

    // 32-bit element offset from the uniform coords base (max 29.5M elems)
    const unsigned pbase = (unsigned)n * (unsigned)(MM * 3 * HW) + (unsigned)hw;

    // NMS state entirely in registers (static indexing only)
    float kx[TOPK], ky[TOPK];
    int   sel[TOPK];
#pragma unroll
    for (int s = 0; s < TOPK; ++s) { kx[s] = BIGV; ky[s] = BIGV; sel[s] = 0; }
    int cnt = 0;

    // preload batch 0
    float X0[MG], X1[MG], X2[MG];
#pragma unroll
    for (int g = 0; g < MG; ++g) {
        unsigned moff = (unsigned)(3 * g) * (unsigned)HW;
        X0[g] = coords[pbase + moff];
        X1[g] = coords[pbase + moff + (unsigned)HW];
        X2[g] = coords[pbase + moff + 2u * (unsigned)HW];
    }

#pragma unroll
    for (int mb = 0; mb < MM; mb += MG) {
        // once every lane has TOPK kept, nothing can change
        if (__all(cnt >= TOPK)) break;

        // prefetch next batch (overlaps current batch's compute)
        float nX0[MG], nX1[MG], nX2[MG];
        if (mb + MG < MM) {
#pragma unroll
            for (int g = 0; g < MG; ++g) {
                unsigned moff = (unsigned)(3 * (mb + MG + g)) * (unsigned)HW;
                nX0[g] = coords[pbase + moff];
                nX1[g] = coords[pbase + moff + (unsigned)HW];
                nX2[g] = coords[pbase + moff + 2u * (unsigned)HW];
            }
        }

        // process current batch (float expressions identical to round-2 kernel)
#pragma unroll
        for (int g = 0; g < MG; ++g) {
            int m = mb + g;
            float xc = p00 * X0[g] + p01 * X1[g] + p02 * X2[g] + p03;
            float yc = p10 * X0[g] + p11 * X1[g] + p12 * X2[g] + p13;
            float zc = p20 * X0[g] + p21 * X1[g] + p22 * X2[g] + p23;
            float z  = fmaxf(zc, EPSV);
            float x  = xc / z;
            float y  = yc / z;

            // any(d2<=THR2)  <=>  min(d2)<=THR2  (no NaNs possible here);
            // fminf tree fuses to v_min3_f32
            float d2[TOPK];
#pragma unroll
            for (int s = 0; s < TOPK; ++s) {
                float dx = kx[s] - x;
                float dy = ky[s] - y;
                d2[s] = dx * dx + dy * dy;
            }
            float md = fminf(fminf(fminf(d2[0], d2[1]), fminf(d2[2], d2[3])),
                             fminf(fminf(d2[4], d2[5]), fminf(d2[6], d2[7])));
            bool keep = (md > THR2) && (cnt < TOPK);
            if (keep) {
#pragma unroll
                for (int s = 0; s < TOPK; ++s) {
                    if (s == cnt) { kx[s] = x; ky[s] = y; sel[s] = m; }
                }
                cnt++;
            }
        }

        // rotate (renamed away by full unroll)
        if (mb + MG < MM) {
#pragma unroll
            for (int g = 0; g < MG; ++g) { X0[g] = nX0[g]; X1[g] = nX1[g]; X2[g] = nX2[g]; }
        }
    }

    // 32 B per thread, consecutive threads -> coalesced int4 stores
    int4* o = reinterpret_cast<int4*>(out + ((size_t)n * HW + hw) * TOPK);
    o[0] = make_int4(sel[0], sel[1], sel[2], sel[3]);
    o[1] = make_int4(sel[4], sel[5], sel[6], sel[7]);
}

extern "C" void kernel_launch(void* const* d_in, const int* in_sizes, int n_in,
                              void* d_out, int out_size, void* d_ws, size_t ws_size,
                              hipStream_t stream) {
    const float* coords = (const float*)d_in[0];   // [N, M, 3, H, W] fp32
    const float* P      = (const float*)d_in[1];   // [N, 3, 4] fp32
    int* out            = (int*)d_out;             // [N, H, W, TOPK] int32

    int N  = in_sizes[1] / 12;                 // 16
    int HW = in_sizes[0] / (N * MM * 3);       // 120*160 = 19200

    if (HW == 19200) {
        dim3 grid(HW / 256, N);                // 75 x 16 blocks, no remainder
        nms_kernel<19200><<<grid, 256, 0, stream>>>(coords, P, out, HW);
    } else {
        dim3 grid((HW + 255) / 256, N);
        nms_kernel<0><<<grid, 256, 0, stream>>>(coords, P, out, HW);
    }
}